// Round 6
// baseline (170.302 us; speedup 1.0000x reference)
//
#include <hip/hip_runtime.h>
#include <stdint.h>

#define SOS_IDX 1
#define EOS_IDX 2
#define Bb 32
#define Tt 256
#define Kk 128
#define PSTR 136   // padded LDS row stride in ushorts (272 B) -> conflict-free b128/b64

typedef unsigned short ushort_t;
typedef __attribute__((ext_vector_type(8))) short short8;   // 8 bf16 (4 VGPRs) - MFMA A/B frag
typedef __attribute__((ext_vector_type(4))) short short4v;  // 4 bf16 (8 B) - epilogue store
typedef __attribute__((ext_vector_type(4))) float float4v;  // MFMA C/D frag

__device__ __forceinline__ ushort_t f2bf(float x) {
    union { float f; uint32_t u; } c; c.f = x;
    uint32_t u = c.u + 0x7FFFu + ((c.u >> 16) & 1u);        // RNE
    return (ushort_t)(u >> 16);
}
__device__ __forceinline__ float bf2f(ushort_t s) {
    union { uint32_t u; float f; } c; c.u = ((uint32_t)s) << 16;
    return c.f;
}

// ---------------- stage A: per-chunk leaf products, transposed form ----------------
// Maintains S = (M_ts * ... * M_t)^T via S_new = diag(eh_t) * (ETT * S_old),
// stored COL-MAJOR: arr[n][k] = S[k][n]  (so arr == Q row-major at the end).
//  * A = ETT: time-invariant -> 16 frags hoisted in regs (no per-step LDS reads)
//  * B = S:   col-major gives [n][k-contig] = exactly the B-frag pattern (b128)
//  * C-write: row dim (q*4+r) contiguous in col-major -> 16 ds_write_b64/lane
//    (round-5's 64 scalar b16 writes were the 1.95M bank-conflict source)
//  * eh/row-max computed in-wave from L1-hit global loads: no ehb/hpart LDS
//  * 1 barrier/step (S and wmax double-buffered)
__global__ __launch_bounds__(256, 1) void crf_stageA(const float* __restrict__ h,
                                                     const float* __restrict__ trans,
                                                     const int* __restrict__ lengths,
                                                     ushort_t* __restrict__ Qt,
                                                     float* __restrict__ Ls,
                                                     int NC, int CSPAN) {
    const int c = blockIdx.x, b = blockIdx.y;
    const int tid = threadIdx.x;
    const int lane = tid & 63, w = tid >> 6;
    const int len = lengths[b];
    int ts = c * CSPAN; if (ts < 1) ts = 1;
    int te = (c + 1) * CSPAN; if (te > Tt) te = Tt;
    const int tE = te < len ? te : len;
    const size_t qoff = ((size_t)b * NC + c) * (Kk * Kk);

    if (ts >= tE) {   // fully masked chunk -> identity
        for (int e = tid; e < Kk * Kk; e += 256)
            Qt[qoff + e] = ((e >> 7) == (e & 127)) ? (ushort_t)0x3F80 : (ushort_t)0;
        if (tid == 0) Ls[(size_t)b * NC + c] = 0.0f;
        return;
    }

    __shared__ __align__(16) ushort_t s_ett[Kk * PSTR];    // ett[m][k] = e^T[k][m]
    __shared__ __align__(16) ushort_t s_S[2][Kk * PSTR];   // col-major S (dbuf)
    __shared__ float s_wmax[2][4];                         // dbuf: kills read/write race

    for (int e = tid; e < Kk * Kk; e += 256) {
        int k = e >> 7, n = e & 127;
        s_ett[n * PSTR + k] = f2bf(__expf(trans[e]));
    }
    // S0 = Identity (first loop iter then produces S = M_ts^T exactly)
    for (int idx = tid; idx < Kk * 16; idx += 256) {
        int a = idx >> 4, b0 = (idx & 15) << 3;
        short8 z = {0, 0, 0, 0, 0, 0, 0, 0};
        if (a >= b0 && a < b0 + 8) z[a - b0] = (short)0x3F80;
        *(short8*)&s_S[0][a * PSTR + b0] = z;
    }
    if (tid < 4) s_wmax[0][tid] = 1.0f;
    __syncthreads();

    const int wr = w >> 1, wc = w & 1, c15 = lane & 15, q = lane >> 4;

    // hoist A-frags (ETT, time-invariant): afr[rt][kt], 64 VGPRs
    short8 afr[4][4];
#pragma unroll
    for (int rt = 0; rt < 4; ++rt)
#pragma unroll
        for (int kt = 0; kt < 4; ++kt)
            afr[rt][kt] = *(const short8*)&s_ett[(wr * 64 + rt * 16 + c15) * PSTR + kt * 32 + q * 8];

    float L = 0.0f;
    int cur = 0;
    for (int t = ts; t < tE; ++t) {
        float G = fmaxf(fmaxf(s_wmax[cur][0], s_wmax[cur][1]),
                        fmaxf(s_wmax[cur][2], s_wmax[cur][3]));
        float invG = 1.0f / G;
        L += __logf(G);

        // row max + eh, fully in-wave (redundant per-wave, L1-hit loads)
        const float* hrow = &h[((size_t)b * Tt + t) * Kk];
        float hm = fmaxf(hrow[lane], hrow[lane + 64]);
#pragma unroll
        for (int o = 1; o < 64; o <<= 1) hm = fmaxf(hm, __shfl_xor(hm, o));
        L += hm;
        float ehg[4][4];                 // eh[m]*invG for my 16 D-rows
#pragma unroll
        for (int rt = 0; rt < 4; ++rt) {
            float4 hv = *(const float4*)&hrow[wr * 64 + rt * 16 + q * 4];
            ehg[rt][0] = __expf(hv.x - hm) * invG;
            ehg[rt][1] = __expf(hv.y - hm) * invG;
            ehg[rt][2] = __expf(hv.z - hm) * invG;
            ehg[rt][3] = __expf(hv.w - hm) * invG;
        }

        // D = ETT * S  (B-frags stream from col-major S)
        float4v acc[4][4];
#pragma unroll
        for (int rt = 0; rt < 4; ++rt)
#pragma unroll
            for (int ct = 0; ct < 4; ++ct) acc[rt][ct] = (float4v){0.f, 0.f, 0.f, 0.f};
        const ushort_t* ps = s_S[cur];
#pragma unroll
        for (int kt = 0; kt < 4; ++kt) {
            short8 bf4[4];
#pragma unroll
            for (int ct = 0; ct < 4; ++ct)
                bf4[ct] = *(const short8*)&ps[(wc * 64 + ct * 16 + c15) * PSTR + kt * 32 + q * 8];
#pragma unroll
            for (int rt = 0; rt < 4; ++rt)
#pragma unroll
                for (int ct = 0; ct < 4; ++ct)
                    acc[rt][ct] = __builtin_amdgcn_mfma_f32_16x16x32_bf16(
                        afr[rt][kt], bf4[ct], acc[rt][ct], 0, 0, 0);
        }

        // epilogue: S_new[m][n] = D[m][n]*eh[m]*invG; col-major write -> b64
        int nxt = cur ^ 1;
        ushort_t* pn = s_S[nxt];
        float lmax = 0.0f;
#pragma unroll
        for (int rt = 0; rt < 4; ++rt) {
#pragma unroll
            for (int ct = 0; ct < 4; ++ct) {
                int base = (wc * 64 + ct * 16 + c15) * PSTR + wr * 64 + rt * 16 + q * 4;
                short4v sv;
#pragma unroll
                for (int r = 0; r < 4; ++r) {
                    float val = acc[rt][ct][r] * ehg[rt][r];
                    lmax = fmaxf(lmax, val);
                    sv[r] = (short)f2bf(val);
                }
                *(short4v*)&pn[base] = sv;
            }
        }
#pragma unroll
        for (int o = 1; o < 64; o <<= 1) lmax = fmaxf(lmax, __shfl_xor(lmax, o));
        if (lane == 0) s_wmax[nxt][w] = lmax;
        __syncthreads();
        cur = nxt;
    }

    // dump: arr == Q row-major; emit Qt[n*128+k] = Q[k][n] (round-5 convention,
    // stage B unchanged). Normalize by final max so stage B sees max==1.
    float Gf = fmaxf(fmaxf(s_wmax[cur][0], s_wmax[cur][1]),
                     fmaxf(s_wmax[cur][2], s_wmax[cur][3]));
    float invGf = 1.0f / Gf;
    L += __logf(Gf);
    const ushort_t* pc = s_S[cur];
#pragma unroll
    for (int r8 = 0; r8 < 8; ++r8) {
        int e8 = (r8 * 256 + tid) * 8;
        int n = e8 >> 7, k0 = e8 & 127;
        uint4 gv;
        ushort_t* gp = (ushort_t*)&gv;
#pragma unroll
        for (int r = 0; r < 8; ++r)
            gp[r] = f2bf(bf2f(pc[(k0 + r) * PSTR + n]) * invGf);
        *(uint4*)&Qt[qoff + e8] = gv;
    }
    if (tid == 0) Ls[(size_t)b * NC + c] = L;
}

// ---------------- stage B: combine chunk products, extract Z_b (round-5 verified) ----
// + gold path score fused into the prologue (saves one kernel launch).
__global__ __launch_bounds__(256, 1) void crf_stageB(const float* __restrict__ h,
                                                     const float* __restrict__ trans,
                                                     const int* __restrict__ y,
                                                     const int* __restrict__ lengths,
                                                     const ushort_t* __restrict__ Qt,
                                                     const float* __restrict__ Ls,
                                                     float* __restrict__ out, int NC) {
    const int b = blockIdx.x;
    const int tid = threadIdx.x;
    const int lane = tid & 63, w = tid >> 6;
    const int wr = w >> 1, wc = w & 1, c15 = lane & 15, q = lane >> 4;
    const int len = lengths[b];

    __shared__ __align__(16) ushort_t s_bq[Kk * PSTR];
    __shared__ __align__(16) ushort_t s_p[2][Kk * PSTR];
    __shared__ float s_wmax[4];
    __shared__ float s_red[4];
    __shared__ float gred[4];

    // ---- fused gold score (t = tid covers all T) ----
    {
        float g = 0.0f;
        if (tid < len) {
            int yt   = y[b * Tt + tid];
            int prev = (tid == 0) ? SOS_IDX : y[b * Tt + tid - 1];
            g = h[((size_t)b * Tt + tid) * Kk + yt] + trans[prev * Kk + yt];
        }
#pragma unroll
        for (int off = 32; off > 0; off >>= 1) g += __shfl_down(g, off);
        if ((tid & 63) == 0) gred[w] = g;
    }

    const size_t lbase = (size_t)b * NC;
    const ushort_t* q0 = Qt + lbase * (Kk * Kk);

    // init P = Q_0 (Qt holds Q^T: P[i][j] = QT[j][i]); one-time uncoalesced ok
    {
        int j = tid & 127, half = tid >> 7;
        for (int i8 = half * 64; i8 < half * 64 + 64; i8 += 8) {
            uint4 g = *(const uint4*)&q0[j * Kk + i8];
            const ushort_t* gs = (const ushort_t*)&g;
#pragma unroll
            for (int r = 0; r < 8; ++r) s_p[0][(i8 + r) * PSTR + j] = gs[r];
        }
    }
    if (tid < 4) s_wmax[tid] = 1.0f;   // stage A normalized Q max to 1
    float L = Ls[lbase];
    __syncthreads();

    if (tid == 0) {
        atomicAdd(out, -(gred[0] + gred[1] + gred[2] + gred[3]) * (1.0f / (float)Bb));
    }

    int cur = 0;
    for (int c = 1; c < NC; ++c) {
        float G = fmaxf(fmaxf(s_wmax[0], s_wmax[1]), fmaxf(s_wmax[2], s_wmax[3]));
        float invG = 1.0f / G;
        L += __logf(G) + Ls[lbase + c];
        const ushort_t* qc = Qt + (lbase + c) * (Kk * Kk);
#pragma unroll
        for (int r8 = 0; r8 < 8; ++r8) {
            int e8 = (r8 * 256 + tid) * 8;
            int n = e8 >> 7, k0 = e8 & 127;
            uint4 g = *(const uint4*)&qc[e8];      // coalesced
            *(uint4*)&s_bq[n * PSTR + k0] = g;
        }
        __syncthreads();                           // bq ready; wmax reads done

        float4v acc[4][4];
#pragma unroll
        for (int rt = 0; rt < 4; ++rt)
#pragma unroll
            for (int ct = 0; ct < 4; ++ct) acc[rt][ct] = (float4v){0.f, 0.f, 0.f, 0.f};
        const ushort_t* pc = s_p[cur];
#pragma unroll
        for (int kt = 0; kt < 4; ++kt) {
            short8 afr[4], bfr[4];
#pragma unroll
            for (int rt = 0; rt < 4; ++rt)
                afr[rt] = *(const short8*)&pc[(wr * 64 + rt * 16 + c15) * PSTR + kt * 32 + q * 8];
#pragma unroll
            for (int ct = 0; ct < 4; ++ct)
                bfr[ct] = *(const short8*)&s_bq[(wc * 64 + ct * 16 + c15) * PSTR + kt * 32 + q * 8];
#pragma unroll
            for (int rt = 0; rt < 4; ++rt)
#pragma unroll
                for (int ct = 0; ct < 4; ++ct)
                    acc[rt][ct] = __builtin_amdgcn_mfma_f32_16x16x32_bf16(
                        afr[rt], bfr[ct], acc[rt][ct], 0, 0, 0);
        }
        int nxt = cur ^ 1;
        ushort_t* pn = s_p[nxt];
        float lmax = 0.0f;
#pragma unroll
        for (int rt = 0; rt < 4; ++rt) {
            int rowb = wr * 64 + rt * 16 + q * 4;
#pragma unroll
            for (int ct = 0; ct < 4; ++ct) {
                int n = wc * 64 + ct * 16 + c15;
#pragma unroll
                for (int r = 0; r < 4; ++r) {
                    float val = acc[rt][ct][r] * invG;
                    lmax = fmaxf(lmax, val);
                    pn[(rowb + r) * PSTR + n] = f2bf(val);
                }
            }
        }
#pragma unroll
        for (int o = 1; o < 64; o <<= 1) lmax = fmaxf(lmax, __shfl_xor(lmax, o));
        if (lane == 0) s_wmax[w] = lmax;
        __syncthreads();
        cur = nxt;
    }

    // Z_b = m0 + L + log( sum_i exp(alpha0[i]-m0) * P[i][EOS] )
    float a0 = -3.0e38f;
    if (tid < 128) a0 = h[((size_t)b * Tt) * Kk + tid] + trans[SOS_IDX * Kk + tid];
    float hm = a0;
#pragma unroll
    for (int o = 1; o < 64; o <<= 1) hm = fmaxf(hm, __shfl_xor(hm, o));
    if (lane == 0) s_red[w] = hm;
    __syncthreads();
    float m0 = fmaxf(fmaxf(s_red[0], s_red[1]), fmaxf(s_red[2], s_red[3]));
    float contrib = 0.0f;
    if (tid < 128) contrib = __expf(a0 - m0) * bf2f(s_p[cur][tid * PSTR + EOS_IDX]);
#pragma unroll
    for (int o = 1; o < 64; o <<= 1) contrib += __shfl_xor(contrib, o);
    __syncthreads();                               // all m0 reads done before s_red reuse
    if (lane == 0) s_red[w] = contrib;
    __syncthreads();
    if (tid == 0) {
        float tot = s_red[0] + s_red[1] + s_red[2] + s_red[3];
        atomicAdd(out, (m0 + L + __logf(tot)) * (1.0f / (float)Bb));
    }
}

extern "C" void kernel_launch(void* const* d_in, const int* in_sizes, int n_in,
                              void* d_out, int out_size, void* d_ws, size_t ws_size,
                              hipStream_t stream) {
    const float* h       = (const float*)d_in[0];
    const float* trans   = (const float*)d_in[1];
    const int*   y       = (const int*)d_in[2];
    const int*   lengths = (const int*)d_in[3];
    // d_in[4] = mask: derived from lengths instead.
    float* out = (float*)d_out;

    int NC = 8;                                    // 8 chunks of 32 steps
    while (NC > 1) {
        size_t need = (size_t)Bb * NC * Kk * Kk * 2 + (size_t)Bb * NC * 4;
        if (need <= ws_size) break;
        NC >>= 1;                                  // degrade gracefully if ws is small
    }
    int CSPAN = Tt / NC;
    ushort_t* Qt = (ushort_t*)d_ws;
    float* Ls = (float*)((char*)d_ws + (size_t)Bb * NC * Kk * Kk * 2);

    hipMemsetAsync(out, 0, sizeof(float), stream);
    crf_stageA<<<dim3(NC, Bb), 256, 0, stream>>>(h, trans, lengths, Qt, Ls, NC, CSPAN);
    crf_stageB<<<Bb, 256, 0, stream>>>(h, trans, y, lengths, Qt, Ls, out, NC);
}

// Round 7
// 160.324 us; speedup vs baseline: 1.0622x; 1.0622x over previous
//
#include <hip/hip_runtime.h>
#include <stdint.h>

#define SOS_IDX 1
#define EOS_IDX 2
#define Bb 32
#define Tt 256
#define Kk 128
#define PSTR 136   // padded LDS row stride in ushorts (272 B) -> conflict-free b128/b64

typedef unsigned short ushort_t;
typedef __attribute__((ext_vector_type(8))) short short8;   // 8 bf16 (4 VGPRs) - MFMA A/B frag
typedef __attribute__((ext_vector_type(4))) short short4v;  // 4 bf16 (8 B) - epilogue store
typedef __attribute__((ext_vector_type(4))) float float4v;  // MFMA C/D frag

__device__ __forceinline__ ushort_t f2bf(float x) {
    union { float f; uint32_t u; } c; c.f = x;
    uint32_t u = c.u + 0x7FFFu + ((c.u >> 16) & 1u);        // RNE
    return (ushort_t)(u >> 16);
}
__device__ __forceinline__ float bf2f(ushort_t s) {
    union { uint32_t u; float f; } c; c.u = ((uint32_t)s) << 16;
    return c.f;
}
__device__ __forceinline__ float bflo(unsigned u) {
    union { uint32_t u; float f; } c; c.u = u << 16; return c.f;
}
__device__ __forceinline__ float bfhi(unsigned u) {
    union { uint32_t u; float f; } c; c.u = u & 0xFFFF0000u; return c.f;
}

// ---------------- stage A: per-chunk leaf products, transposed form ----------------
// S = (M_ts*...*M_t)^T via S_new = diag(eh_t)*(ETT*S_old), col-major storage.
// Round-6 postmortem: 1 wave/SIMD (Occupancy 4.7%) left every latency exposed
// (~6600 cyc/step vs ~2500 of throughput work). Fixes here:
//  * NC=16 -> 512 blocks -> 2 blocks/CU (independent barrier domains overlap).
//    LDS cut to one dbuf pair (69.6 KB) by staging ETT into s_S[1], which the
//    first loop iteration only overwrites AFTER A-frags are hoisted to regs.
//  * h-row register prefetch restored (round 6 dropped it: 89->93 us).
__global__ __launch_bounds__(256, 2) void crf_stageA(const float* __restrict__ h,
                                                     const float* __restrict__ trans,
                                                     const int* __restrict__ lengths,
                                                     ushort_t* __restrict__ Qt,
                                                     float* __restrict__ Ls,
                                                     int NC, int CSPAN) {
    const int c = blockIdx.x, b = blockIdx.y;
    const int tid = threadIdx.x;
    const int lane = tid & 63, w = tid >> 6;
    const int len = lengths[b];
    int ts = c * CSPAN; if (ts < 1) ts = 1;
    int te = (c + 1) * CSPAN; if (te > Tt) te = Tt;
    const int tE = te < len ? te : len;
    const size_t qoff = ((size_t)b * NC + c) * (Kk * Kk);

    if (ts >= tE) {   // fully masked chunk -> identity
        for (int e = tid; e < Kk * Kk; e += 256)
            Qt[qoff + e] = ((e >> 7) == (e & 127)) ? (ushort_t)0x3F80 : (ushort_t)0;
        if (tid == 0) Ls[(size_t)b * NC + c] = 0.0f;
        return;
    }

    __shared__ __align__(16) ushort_t s_S[2][Kk * PSTR];   // col-major S (dbuf)
    __shared__ float s_wmax[2][4];                         // dbuf: kills read/write race

    // stage ETT into s_S[1]: ett[m][k] = e^T[k][m]. Coalesced trans reads.
    for (int e = tid; e < Kk * Kk; e += 256) {
        int k = e >> 7, n = e & 127;
        s_S[1][n * PSTR + k] = f2bf(__expf(trans[e]));
    }
    __syncthreads();                               // ETT staged

    const int wr = w >> 1, wc = w & 1, c15 = lane & 15, q = lane >> 4;

    // hoist A-frags (ETT, time-invariant): afr[rt][kt], 64 VGPRs
    short8 afr[4][4];
#pragma unroll
    for (int rt = 0; rt < 4; ++rt)
#pragma unroll
        for (int kt = 0; kt < 4; ++kt)
            afr[rt][kt] = *(const short8*)&s_S[1][(wr * 64 + rt * 16 + c15) * PSTR + kt * 32 + q * 8];

    // S0 = Identity in s_S[0] (first loop iter produces S = M_ts^T exactly)
    for (int idx = tid; idx < Kk * 16; idx += 256) {
        int a = idx >> 4, b0 = (idx & 15) << 3;
        short8 z = {0, 0, 0, 0, 0, 0, 0, 0};
        if (a >= b0 && a < b0 + 8) z[a - b0] = (short)0x3F80;
        *(short8*)&s_S[0][a * PSTR + b0] = z;
    }
    if (tid < 4) s_wmax[0][tid] = 1.0f;

    // prefetch first h row into regs (covers whole 512B row across 64 lanes -> L1)
    const float* hbase = &h[((size_t)b * Tt) * Kk];
    float hA = hbase[(size_t)ts * Kk + lane];
    float hB = hbase[(size_t)ts * Kk + lane + 64];
    __syncthreads();   // afr-hoist reads of s_S[1] done before iter-1 overwrites it

    float L = 0.0f;
    int cur = 0;
    for (int t = ts; t < tE; ++t) {
        float hcA = hA, hcB = hB;                  // current row (loaded last iter)
        if (t + 1 < tE) {                          // prefetch next row early
            hA = hbase[(size_t)(t + 1) * Kk + lane];
            hB = hbase[(size_t)(t + 1) * Kk + lane + 64];
        }
        float G = fmaxf(fmaxf(s_wmax[cur][0], s_wmax[cur][1]),
                        fmaxf(s_wmax[cur][2], s_wmax[cur][3]));
        float invG = 1.0f / G;
        L += __logf(G);

        float hm = fmaxf(hcA, hcB);
#pragma unroll
        for (int o = 1; o < 64; o <<= 1) hm = fmaxf(hm, __shfl_xor(hm, o));
        L += hm;
        float ehg[4][4];                 // eh[m]*invG for my 16 D-rows (L1-hot re-reads)
#pragma unroll
        for (int rt = 0; rt < 4; ++rt) {
            float4 hv = *(const float4*)&hbase[(size_t)t * Kk + wr * 64 + rt * 16 + q * 4];
            ehg[rt][0] = __expf(hv.x - hm) * invG;
            ehg[rt][1] = __expf(hv.y - hm) * invG;
            ehg[rt][2] = __expf(hv.z - hm) * invG;
            ehg[rt][3] = __expf(hv.w - hm) * invG;
        }

        // D = ETT * S  (B-frags stream from col-major S)
        float4v acc[4][4];
#pragma unroll
        for (int rt = 0; rt < 4; ++rt)
#pragma unroll
            for (int ct = 0; ct < 4; ++ct) acc[rt][ct] = (float4v){0.f, 0.f, 0.f, 0.f};
        const ushort_t* ps = s_S[cur];
#pragma unroll
        for (int kt = 0; kt < 4; ++kt) {
            short8 bf4[4];
#pragma unroll
            for (int ct = 0; ct < 4; ++ct)
                bf4[ct] = *(const short8*)&ps[(wc * 64 + ct * 16 + c15) * PSTR + kt * 32 + q * 8];
#pragma unroll
            for (int rt = 0; rt < 4; ++rt)
#pragma unroll
                for (int ct = 0; ct < 4; ++ct)
                    acc[rt][ct] = __builtin_amdgcn_mfma_f32_16x16x32_bf16(
                        afr[rt][kt], bf4[ct], acc[rt][ct], 0, 0, 0);
        }

        // epilogue: S_new[m][n] = D[m][n]*eh[m]*invG; col-major write -> b64
        int nxt = cur ^ 1;
        ushort_t* pn = s_S[nxt];
        float lmax = 0.0f;
#pragma unroll
        for (int rt = 0; rt < 4; ++rt) {
#pragma unroll
            for (int ct = 0; ct < 4; ++ct) {
                int base = (wc * 64 + ct * 16 + c15) * PSTR + wr * 64 + rt * 16 + q * 4;
                short4v sv;
#pragma unroll
                for (int r = 0; r < 4; ++r) {
                    float val = acc[rt][ct][r] * ehg[rt][r];
                    lmax = fmaxf(lmax, val);
                    sv[r] = (short)f2bf(val);
                }
                *(short4v*)&pn[base] = sv;
            }
        }
#pragma unroll
        for (int o = 1; o < 64; o <<= 1) lmax = fmaxf(lmax, __shfl_xor(lmax, o));
        if (lane == 0) s_wmax[nxt][w] = lmax;
        __syncthreads();
        cur = nxt;
    }

    // dump: arr == Q row-major; Qt[n*128+k] = Q[k][n]. Normalize so max==1.
    float Gf = fmaxf(fmaxf(s_wmax[cur][0], s_wmax[cur][1]),
                     fmaxf(s_wmax[cur][2], s_wmax[cur][3]));
    float invGf = 1.0f / Gf;
    L += __logf(Gf);
    const ushort_t* pc = s_S[cur];
#pragma unroll
    for (int r8 = 0; r8 < 8; ++r8) {
        int e8 = (r8 * 256 + tid) * 8;
        int n = e8 >> 7, k0 = e8 & 127;
        uint4 gv;
        ushort_t* gp = (ushort_t*)&gv;
#pragma unroll
        for (int r = 0; r < 8; ++r)
            gp[r] = f2bf(bf2f(pc[(k0 + r) * PSTR + n]) * invGf);
        *(uint4*)&Qt[qoff + e8] = gv;
    }
    if (tid == 0) Ls[(size_t)b * NC + c] = L;
}

// ---------------- stage B: VECTOR chain v <- v*Q_c, extract Z_b ----------------
// Z only needs alpha0^T * Q_0 * ... * Q_{NC-1} at EOS: propagate the 128-vector
// (one 128x128 mat-vec per chunk, ~400 cyc) instead of round-6's 128x128 matrix
// chain (~7000 cyc each). Lane pair (2n,2n+1) owns v_new[n]; half=tid&1 dots
// k in [64*half, 64*half+64) -- contiguous in Qt (Qt[n*128+k] = Q[k][n]).
// Lag-1 max normalization (f32, growth <= 128x/step -> safe); gold fused.
__global__ __launch_bounds__(256, 1) void crf_stageB(const float* __restrict__ h,
                                                     const float* __restrict__ trans,
                                                     const int* __restrict__ y,
                                                     const int* __restrict__ lengths,
                                                     const ushort_t* __restrict__ Qt,
                                                     const float* __restrict__ Ls,
                                                     float* __restrict__ out, int NC) {
    const int b = blockIdx.x;
    const int tid = threadIdx.x;
    const int lane = tid & 63, w = tid >> 6;
    const int n = tid >> 1, half = tid & 1;
    const int len = lengths[b];

    __shared__ __align__(16) float vbuf[2][Kk];
    __shared__ float s_wmax[2][4];
    __shared__ float red[4];
    __shared__ float gred[4];

    // ---- fused gold score (t = tid covers all T) ----
    {
        float g = 0.0f;
        if (tid < len) {
            int yt   = y[b * Tt + tid];
            int prev = (tid == 0) ? SOS_IDX : y[b * Tt + tid - 1];
            g = h[((size_t)b * Tt + tid) * Kk + yt] + trans[prev * Kk + yt];
        }
#pragma unroll
        for (int off = 32; off > 0; off >>= 1) g += __shfl_down(g, off);
        if (lane == 0) gred[w] = g;
    }

    // ---- init v0 = exp(alpha0 - m0) ----
    float a0 = h[((size_t)b * Tt) * Kk + n] + trans[SOS_IDX * Kk + n];
    float m0 = a0;
#pragma unroll
    for (int o = 1; o < 64; o <<= 1) m0 = fmaxf(m0, __shfl_xor(m0, o));
    if (lane == 0) red[w] = m0;
    __syncthreads();
    m0 = fmaxf(fmaxf(red[0], red[1]), fmaxf(red[2], red[3]));
    float cacc = m0;
    if (half == 0) vbuf[0][n] = __expf(a0 - m0);    // max == 1 exactly
    if (tid < 4) s_wmax[0][tid] = 1.0f;
    if (tid == 0)
        atomicAdd(out, -(gred[0] + gred[1] + gred[2] + gred[3]) * (1.0f / (float)Bb));
    __syncthreads();

    const size_t lbase = (size_t)b * NC;
    int cur = 0;
    for (int ci = 0; ci < NC; ++ci) {
        const uint4* qp = (const uint4*)(Qt + (lbase + ci) * (Kk * Kk) + n * Kk + half * 64);
        float G = fmaxf(fmaxf(s_wmax[cur][0], s_wmax[cur][1]),
                        fmaxf(s_wmax[cur][2], s_wmax[cur][3]));
        float invG = 1.0f / G;
        cacc += __logf(G) + Ls[lbase + ci];

        float acc0 = 0.0f, acc1 = 0.0f;
#pragma unroll
        for (int r = 0; r < 8; ++r) {
            uint4 d = qp[r];                        // 8 bf16 of Q-column n
            float4 v0 = *(const float4*)&vbuf[cur][half * 64 + r * 8];
            float4 v1 = *(const float4*)&vbuf[cur][half * 64 + r * 8 + 4];
            acc0 = fmaf(bflo(d.x), v0.x, acc0);
            acc1 = fmaf(bfhi(d.x), v0.y, acc1);
            acc0 = fmaf(bflo(d.y), v0.z, acc0);
            acc1 = fmaf(bfhi(d.y), v0.w, acc1);
            acc0 = fmaf(bflo(d.z), v1.x, acc0);
            acc1 = fmaf(bfhi(d.z), v1.y, acc1);
            acc0 = fmaf(bflo(d.w), v1.z, acc0);
            acc1 = fmaf(bfhi(d.w), v1.w, acc1);
        }
        float s = (acc0 + acc1) * invG;
        s += __shfl_xor(s, 1);                      // pair combine: full v_new[n]

        float wm = s;
#pragma unroll
        for (int o = 1; o < 64; o <<= 1) wm = fmaxf(wm, __shfl_xor(wm, o));
        int nxt = cur ^ 1;
        if (half == 0) vbuf[nxt][n] = s;
        if (lane == 0) s_wmax[nxt][w] = wm;
        __syncthreads();
        cur = nxt;
    }

    // Z_b = cacc + log(v_final[EOS])  (final wmax intentionally not folded)
    if (tid == 0) {
        atomicAdd(out, (cacc + __logf(vbuf[cur][EOS_IDX])) * (1.0f / (float)Bb));
    }
}

extern "C" void kernel_launch(void* const* d_in, const int* in_sizes, int n_in,
                              void* d_out, int out_size, void* d_ws, size_t ws_size,
                              hipStream_t stream) {
    const float* h       = (const float*)d_in[0];
    const float* trans   = (const float*)d_in[1];
    const int*   y       = (const int*)d_in[2];
    const int*   lengths = (const int*)d_in[3];
    // d_in[4] = mask: derived from lengths instead.
    float* out = (float*)d_out;

    int NC = 16;                                   // 16 chunks of 16 steps -> 2 blocks/CU
    while (NC > 1) {
        size_t need = (size_t)Bb * NC * Kk * Kk * 2 + (size_t)Bb * NC * 4;
        if (need <= ws_size) break;
        NC >>= 1;                                  // degrade gracefully if ws is small
    }
    int CSPAN = Tt / NC;
    ushort_t* Qt = (ushort_t*)d_ws;
    float* Ls = (float*)((char*)d_ws + (size_t)Bb * NC * Kk * Kk * 2);

    hipMemsetAsync(out, 0, sizeof(float), stream);
    crf_stageA<<<dim3(NC, Bb), 256, 0, stream>>>(h, trans, lengths, Qt, Ls, NC, CSPAN);
    crf_stageB<<<Bb, 256, 0, stream>>>(h, trans, y, lengths, Qt, Ls, out, NC);
}

// Round 8
// 151.441 us; speedup vs baseline: 1.1245x; 1.0587x over previous
//
#include <hip/hip_runtime.h>
#include <stdint.h>

#define SOS_IDX 1
#define EOS_IDX 2
#define Bb 32
#define Tt 256
#define Kk 128
#define SK 136          // padded k-stride in ushorts (272 B) -> conflict-free b64/b128
#define MAXSPAN 64      // s_eh row capacity (supports NC >= 4)

typedef unsigned short ushort_t;
typedef __attribute__((ext_vector_type(8))) short short8;   // 8 bf16 = 4 VGPR (MFMA A/B)
typedef __attribute__((ext_vector_type(4))) float float4v;  // MFMA C/D

__device__ __forceinline__ ushort_t f2bf(float x) {
    union { float f; uint32_t u; } c; c.f = x;
    uint32_t u = c.u + 0x7FFFu + ((c.u >> 16) & 1u);        // RNE (cold paths)
    return (ushort_t)(u >> 16);
}
__device__ __forceinline__ float bflo(uint32_t u) {
    union { uint32_t u; float f; } c; c.u = u << 16; return c.f;
}
__device__ __forceinline__ float bfhi(uint32_t u) {
    union { uint32_t u; float f; } c; c.u = u & 0xFFFF0000u; return c.f;
}
// pack two f32 -> two bf16 (round-half-up) in ONE v_perm: result = [hi16(b+0.5ulp) : hi16(a+0.5ulp)]
__device__ __forceinline__ uint32_t pk2bf(float a, float b) {
    union { float f; uint32_t u; } ca, cb; ca.f = a; cb.f = b;
    return __builtin_amdgcn_perm(cb.u + 0x8000u, ca.u + 0x8000u, 0x07060302u);
}

// ---------------- stage A: chunk products, barrier-free wave-private stripes --------
// Column n of S_new = diag(eh)*(ETT*S_old) depends only on column n of S_old, so the
// 128x128 product splits into 4 independent 32-col stripes (one per wave):
//   * A = ETT hoisted to 128 VGPRs (time-invariant)
//   * B = own stripe, 8 frags = 32 VGPRs
//   * D->B' transpose through wave-PRIVATE LDS scratch (b64 col-major write +
//     b128 read = round-6-proven pair); same-wave DS ordering -> NO barrier in loop
//   * EH[t][k] pre-staged once per chunk (prologue), removing in-loop exps
//   * per-wave scale L_w; one end-barrier reconciles stripes into a single L
// launch_bounds(256,1): 1 wave/SIMD by design -> 512-VGPR budget, no spill (~310 used).
__global__ __launch_bounds__(256, 1) void crf_stageA(const float* __restrict__ h,
                                                     const float* __restrict__ trans,
                                                     const int* __restrict__ lengths,
                                                     ushort_t* __restrict__ Qt,
                                                     float* __restrict__ Ls,
                                                     int NC, int CSPAN) {
    const int c = blockIdx.x, b = blockIdx.y;
    const int tid = threadIdx.x;
    const int lane = tid & 63, w = tid >> 6;
    const int c15 = lane & 15, q = lane >> 4;
    const int len = lengths[b];
    int ts = c * CSPAN; if (ts < 1) ts = 1;
    int te = (c + 1) * CSPAN; if (te > Tt) te = Tt;
    const int tE = te < len ? te : len;
    const size_t qoff = ((size_t)b * NC + c) * (Kk * Kk);

    if (ts >= tE) {   // fully masked chunk -> identity (coalesced uint4 writes)
        for (int e = tid; e < 2048; e += 256) {
            int n = e >> 4, k8 = (e & 15) * 8;
            uint4 gv; ushort_t* gp = (ushort_t*)&gv;
#pragma unroll
            for (int r = 0; r < 8; ++r) gp[r] = (n == k8 + r) ? (ushort_t)0x3F80 : (ushort_t)0;
            *(uint4*)&Qt[qoff + (size_t)n * Kk + k8] = gv;
        }
        if (tid == 0) Ls[(size_t)b * NC + c] = 0.0f;
        return;
    }
    const int nsteps = tE - ts;

    __shared__ __align__(16) ushort_t s_ett[Kk * SK];      // ett[m][k] = e^T[k][m]
    __shared__ __align__(16) float    s_eh[MAXSPAN][Kk];   // exp(h - hm) per step
    __shared__ __align__(16) ushort_t s_w[4][32 * SK];     // wave-private transpose scratch
    __shared__ float s_hms[4], s_L[4];

    for (int e = tid; e < Kk * Kk; e += 256) {
        int k = e >> 7, n = e & 127;
        s_ett[n * SK + k] = f2bf(__expf(trans[e]));
    }
    // EH staging: wave w handles rows tl = 4*i + w
    float hms = 0.0f;
    for (int i = 0; i < MAXSPAN / 4; ++i) {
        int tl = i * 4 + w;
        if (tl < nsteps) {
            const float* hr = &h[((size_t)b * Tt + ts + tl) * Kk];
            float h0 = hr[lane], h1 = hr[lane + 64];
            float hm = fmaxf(h0, h1);
#pragma unroll
            for (int o = 1; o < 64; o <<= 1) hm = fmaxf(hm, __shfl_xor(hm, o));
            s_eh[tl][lane]      = __expf(h0 - hm);
            s_eh[tl][lane + 64] = __expf(h1 - hm);
            hms += hm;                                  // wave-uniform
        }
    }
    if (lane == 0) s_hms[w] = hms;
    __syncthreads();                                    // barrier #1 (staging done)
    const float hmsum = s_hms[0] + s_hms[1] + s_hms[2] + s_hms[3];

    // hoist A-frags: full ETT, 8(mt) x 4(kt) x 4 VGPR = 128 VGPRs
    short8 afr[8][4];
#pragma unroll
    for (int mt = 0; mt < 8; ++mt)
#pragma unroll
        for (int kt = 0; kt < 4; ++kt)
            afr[mt][kt] = *(const short8*)&s_ett[(mt * 16 + c15) * SK + kt * 32 + q * 8];

    // B = Identity frags for my stripe (n in [32w, 32w+32))
    short8 bfr[4][2];
#pragma unroll
    for (int kt = 0; kt < 4; ++kt)
#pragma unroll
        for (int ct = 0; ct < 2; ++ct) {
            short8 z;
#pragma unroll
            for (int j = 0; j < 8; ++j) {
                int k = kt * 32 + q * 8 + j;
                int n = w * 32 + ct * 16 + c15;
                z[j] = (k == n) ? (short)0x3F80 : (short)0;
            }
            bfr[kt][ct] = z;
        }

    ushort_t* swp = &s_w[w][0];
    float G = 1.0f, Lw = 0.0f;
    for (int s = 0; s < nsteps; ++s) {
        float invG = 1.0f / G;
        Lw += __logf(G);
        float sc[8][4];                                 // EH[s][m]*invG, broadcast LDS reads
#pragma unroll
        for (int mt = 0; mt < 8; ++mt) {
            float4 t4 = *(const float4*)&s_eh[s][mt * 16 + q * 4];
            sc[mt][0] = t4.x * invG; sc[mt][1] = t4.y * invG;
            sc[mt][2] = t4.z * invG; sc[mt][3] = t4.w * invG;
        }
        float4v D[8][2];
#pragma unroll
        for (int mt = 0; mt < 8; ++mt)
#pragma unroll
            for (int ct = 0; ct < 2; ++ct) D[mt][ct] = (float4v){0.f, 0.f, 0.f, 0.f};
#pragma unroll
        for (int kt = 0; kt < 4; ++kt)
#pragma unroll
            for (int mt = 0; mt < 8; ++mt)
#pragma unroll
                for (int ct = 0; ct < 2; ++ct)
                    D[mt][ct] = __builtin_amdgcn_mfma_f32_16x16x32_bf16(
                        afr[mt][kt], bfr[kt][ct], D[mt][ct], 0, 0, 0);

        // S'[m][n] = D*eh[m]*invG: pack (round-half-up, 1 perm / 2 vals), b64 col-major
        float lmax = 0.0f;
#pragma unroll
        for (int mt = 0; mt < 8; ++mt)
#pragma unroll
            for (int ct = 0; ct < 2; ++ct) {
                float v0 = D[mt][ct][0] * sc[mt][0];
                float v1 = D[mt][ct][1] * sc[mt][1];
                float v2 = D[mt][ct][2] * sc[mt][2];
                float v3 = D[mt][ct][3] * sc[mt][3];
                lmax = fmaxf(lmax, fmaxf(fmaxf(v0, v1), fmaxf(v2, v3)));
                uint2 u; u.x = pk2bf(v0, v1); u.y = pk2bf(v2, v3);
                *(uint2*)&swp[(ct * 16 + c15) * SK + mt * 16 + q * 4] = u;
            }
        // read back B' (same-wave DS ordering; no barrier)
#pragma unroll
        for (int kt = 0; kt < 4; ++kt)
#pragma unroll
            for (int ct = 0; ct < 2; ++ct)
                bfr[kt][ct] = *(const short8*)&swp[(ct * 16 + c15) * SK + kt * 32 + q * 8];
#pragma unroll
        for (int o = 1; o < 64; o <<= 1) lmax = fmaxf(lmax, __shfl_xor(lmax, o));
        G = lmax;                                       // lag-1: divided out next step
    }
    Lw += __logf(G);                                    // pending final scale

    if (lane == 0) s_L[w] = Lw;
    __syncthreads();                                    // barrier #2 (stripe-L exchange)
    float Lmax = fmaxf(fmaxf(s_L[0], s_L[1]), fmaxf(s_L[2], s_L[3]));
    float dsc = __expf(Lw - Lmax) / G;                  // stripe rescale to common L

    // dump my stripe: Qt[n*128+k] = Q[k][n]; scratch is [n_local][k] -> coalesced
    for (int it = lane; it < 32 * 16; it += 64) {
        int nl = it >> 4, k8 = (it & 15) * 8;
        uint4 rv = *(const uint4*)&swp[nl * SK + k8];
        uint4 gv;
        gv.x = pk2bf(bflo(rv.x) * dsc, bfhi(rv.x) * dsc);
        gv.y = pk2bf(bflo(rv.y) * dsc, bfhi(rv.y) * dsc);
        gv.z = pk2bf(bflo(rv.z) * dsc, bfhi(rv.z) * dsc);
        gv.w = pk2bf(bflo(rv.w) * dsc, bfhi(rv.w) * dsc);
        *(uint4*)&Qt[qoff + (size_t)(w * 32 + nl) * Kk + k8] = gv;
    }
    if (tid == 0) Ls[(size_t)b * NC + c] = Lmax + hmsum;
}

// ---------------- stage B: vector chain with register prefetch ----------------
// Round-7 body (proven) + chunk c+1's 128 B/thread prefetched into registers
// during chunk c's dot (loads are independent of the vbuf recurrence), hiding
// the ~1000-cyc cold-read latency that dominated round 7.
__global__ __launch_bounds__(256, 1) void crf_stageB(const float* __restrict__ h,
                                                     const float* __restrict__ trans,
                                                     const int* __restrict__ y,
                                                     const int* __restrict__ lengths,
                                                     const ushort_t* __restrict__ Qt,
                                                     const float* __restrict__ Ls,
                                                     float* __restrict__ out, int NC) {
    const int b = blockIdx.x;
    const int tid = threadIdx.x;
    const int lane = tid & 63, w = tid >> 6;
    const int n = tid >> 1, half = tid & 1;
    const int len = lengths[b];

    __shared__ __align__(16) float vbuf[2][Kk];
    __shared__ float s_wmax[2][4];
    __shared__ float red[4];
    __shared__ float gred[4];

    // ---- fused gold score ----
    {
        float g = 0.0f;
        if (tid < len) {
            int yt   = y[b * Tt + tid];
            int prev = (tid == 0) ? SOS_IDX : y[b * Tt + tid - 1];
            g = h[((size_t)b * Tt + tid) * Kk + yt] + trans[prev * Kk + yt];
        }
#pragma unroll
        for (int off = 32; off > 0; off >>= 1) g += __shfl_down(g, off);
        if (lane == 0) gred[w] = g;
    }

    // ---- init v0 = exp(alpha0 - m0) ----
    float a0 = h[((size_t)b * Tt) * Kk + n] + trans[SOS_IDX * Kk + n];
    float m0 = a0;
#pragma unroll
    for (int o = 1; o < 64; o <<= 1) m0 = fmaxf(m0, __shfl_xor(m0, o));
    if (lane == 0) red[w] = m0;
    __syncthreads();
    m0 = fmaxf(fmaxf(red[0], red[1]), fmaxf(red[2], red[3]));
    float cacc = m0;
    if (half == 0) vbuf[0][n] = __expf(a0 - m0);
    if (tid < 4) s_wmax[0][tid] = 1.0f;
    if (tid == 0)
        atomicAdd(out, -(gred[0] + gred[1] + gred[2] + gred[3]) * (1.0f / (float)Bb));
    __syncthreads();

    const size_t lbase = (size_t)b * NC;
    uint4 qb[8];
    {
        const uint4* qp = (const uint4*)(Qt + lbase * (Kk * Kk) + n * Kk + half * 64);
#pragma unroll
        for (int r = 0; r < 8; ++r) qb[r] = qp[r];
    }

    int cur = 0;
    for (int ci = 0; ci < NC; ++ci) {
        uint4 qn[8];
        if (ci + 1 < NC) {                              // prefetch next chunk early
            const uint4* qp2 = (const uint4*)(Qt + (lbase + ci + 1) * (Kk * Kk) + n * Kk + half * 64);
#pragma unroll
            for (int r = 0; r < 8; ++r) qn[r] = qp2[r];
        }
        float G = fmaxf(fmaxf(s_wmax[cur][0], s_wmax[cur][1]),
                        fmaxf(s_wmax[cur][2], s_wmax[cur][3]));
        float invG = 1.0f / G;
        cacc += __logf(G) + Ls[lbase + ci];

        float acc0 = 0.0f, acc1 = 0.0f;
#pragma unroll
        for (int r = 0; r < 8; ++r) {
            uint4 d = qb[r];
            float4 v0 = *(const float4*)&vbuf[cur][half * 64 + r * 8];
            float4 v1 = *(const float4*)&vbuf[cur][half * 64 + r * 8 + 4];
            acc0 = fmaf(bflo(d.x), v0.x, acc0);
            acc1 = fmaf(bfhi(d.x), v0.y, acc1);
            acc0 = fmaf(bflo(d.y), v0.z, acc0);
            acc1 = fmaf(bfhi(d.y), v0.w, acc1);
            acc0 = fmaf(bflo(d.z), v1.x, acc0);
            acc1 = fmaf(bfhi(d.z), v1.y, acc1);
            acc0 = fmaf(bflo(d.w), v1.z, acc0);
            acc1 = fmaf(bfhi(d.w), v1.w, acc1);
        }
        float s = (acc0 + acc1) * invG;
        s += __shfl_xor(s, 1);                          // pair combine

        float wm = s;
#pragma unroll
        for (int o = 1; o < 64; o <<= 1) wm = fmaxf(wm, __shfl_xor(wm, o));
        int nxt = cur ^ 1;
        if (half == 0) vbuf[nxt][n] = s;
        if (lane == 0) s_wmax[nxt][w] = wm;
        __syncthreads();
        cur = nxt;
        if (ci + 1 < NC) {
#pragma unroll
            for (int r = 0; r < 8; ++r) qb[r] = qn[r];
        }
    }

    if (tid == 0) {
        atomicAdd(out, (cacc + __logf(vbuf[cur][EOS_IDX])) * (1.0f / (float)Bb));
    }
}

extern "C" void kernel_launch(void* const* d_in, const int* in_sizes, int n_in,
                              void* d_out, int out_size, void* d_ws, size_t ws_size,
                              hipStream_t stream) {
    const float* h       = (const float*)d_in[0];
    const float* trans   = (const float*)d_in[1];
    const int*   y       = (const int*)d_in[2];
    const int*   lengths = (const int*)d_in[3];
    // d_in[4] = mask: derived from lengths instead.
    float* out = (float*)d_out;

    int NC = 8;                                    // 8 chunks of 32 steps (256 blocks, 1/CU)
    while (NC > 4) {                               // floor 4: s_eh sized for CSPAN<=64
        size_t need = (size_t)Bb * NC * Kk * Kk * 2 + (size_t)Bb * NC * 4;
        if (need <= ws_size) break;
        NC >>= 1;
    }
    int CSPAN = Tt / NC;
    ushort_t* Qt = (ushort_t*)d_ws;
    float* Ls = (float*)((char*)d_ws + (size_t)Bb * NC * Kk * Kk * 2);

    hipMemsetAsync(out, 0, sizeof(float), stream);
    crf_stageA<<<dim3(NC, Bb), 256, 0, stream>>>(h, trans, lengths, Qt, Ls, NC, CSPAN);
    crf_stageB<<<Bb, 256, 0, stream>>>(h, trans, y, lengths, Qt, Ls, out, NC);
}

// Round 9
// 136.731 us; speedup vs baseline: 1.2455x; 1.1076x over previous
//
#include <hip/hip_runtime.h>
#include <stdint.h>

#define SOS_IDX 1
#define EOS_IDX 2
#define Bb 32
#define Tt 256
#define Kk 128
#define SK 136          // padded k-stride in ushorts (272 B) -> conflict-free b64/b128

typedef unsigned short ushort_t;
typedef __attribute__((ext_vector_type(8))) short short8;   // 8 bf16 = 4 VGPR (MFMA A/B)
typedef __attribute__((ext_vector_type(4))) float float4v;  // MFMA C/D

__device__ __forceinline__ ushort_t f2bf(float x) {         // RNE
    union { float f; uint32_t u; } c; c.f = x;
    uint32_t u = c.u + 0x7FFFu + ((c.u >> 16) & 1u);
    return (ushort_t)(u >> 16);
}
__device__ __forceinline__ float bf2f(ushort_t s) {
    union { uint32_t u; float f; } c; c.u = ((uint32_t)s) << 16;
    return c.f;
}
__device__ __forceinline__ float bflo(uint32_t u) {
    union { uint32_t u; float f; } c; c.u = u << 16; return c.f;
}
__device__ __forceinline__ float bfhi(uint32_t u) {
    union { uint32_t u; float f; } c; c.u = u & 0xFFFF0000u; return c.f;
}
// pack two f32 -> bf16x2 with RNE (one v_perm after the rounding adds)
__device__ __forceinline__ uint32_t pk2bf(float a, float b) {
    union { float f; uint32_t u; } ca, cb; ca.f = a; cb.f = b;
    uint32_t ua = ca.u + 0x7FFFu + ((ca.u >> 16) & 1u);
    uint32_t ub = cb.u + 0x7FFFu + ((cb.u >> 16) & 1u);
    return __builtin_amdgcn_perm(ub, ua, 0x07060302u);
}

// ---------------- stage A: block = (batch, chunk, 32-col stripe) ----------------
// S = (M_ts*...*M_t)^T evolves col-independently: this block owns S-cols
// [32*st, 32*st+32). 4 waves split the m (row) dimension, 32 rows each:
//  * A-frags (ETT rows of my wave) = 8 frags = 32 VGPRs -- small enough that the
//    allocator keeps them (R1/R2/R8 evidence: hoists >~64 regs get spilled)
//  * B = stripe in LDS (17.5 KB/block -> 4+ blocks/CU co-resident; R7 evidence:
//    co-resident blocks with independent barriers are the only effective
//    latency-hiding for this barrier-serial recurrence)
//  * eh = exp(h) directly (|h|<~5, no max-subtract needed); 2 broadcast L1
//    dwordx4 loads/wave/step, register-prefetched one step ahead
//  * per-step: 8 ds_read_b128 + 16 MFMA + 4 ds_write_b64 + 1 barrier per wave
// Dump uses the R6/R7-VERIFIED orientation Qt[n][k] = S[n][k] (R8 had it
// transposed -> absmax 4.0); RNE packing everywhere.
__global__ __launch_bounds__(256, 2) void crf_stageA(const float* __restrict__ h,
                                                     const float* __restrict__ trans,
                                                     const int* __restrict__ lengths,
                                                     ushort_t* __restrict__ Qt,
                                                     float* __restrict__ Ls,
                                                     int NC, int CSPAN) {
    const int st = blockIdx.x, c = blockIdx.y, b = blockIdx.z;
    const int tid = threadIdx.x;
    const int lane = tid & 63, w = tid >> 6;
    const int c15 = lane & 15, q = lane >> 4;
    const int len = lengths[b];
    int ts = c * CSPAN; if (ts < 1) ts = 1;
    int te = (c + 1) * CSPAN; if (te > Tt) te = Tt;
    const int tE = te < len ? te : len;
    const size_t qoff = ((size_t)b * NC + c) * (Kk * Kk);
    const int nbase = st * 32;                 // my k-columns of Qt

    if (ts >= tE) {   // fully masked chunk -> identity slice
#pragma unroll
        for (int j = 0; j < 2; ++j) {
            int idx = j * 256 + tid;           // 512 items: n = idx&127, o = idx>>7
            int n = idx & 127, o = idx >> 7;
            uint4 gv; ushort_t* gp = (ushort_t*)&gv;
#pragma unroll
            for (int r = 0; r < 8; ++r) gp[r] = (n == nbase + o * 8 + r) ? (ushort_t)0x3F80 : (ushort_t)0;
            *(uint4*)&Qt[qoff + (size_t)n * Kk + nbase + o * 8] = gv;
        }
        if (tid == 0) Ls[(((size_t)b * NC + c) << 2) + st] = 0.0f;
        return;
    }

    __shared__ __align__(16) ushort_t s_S[2][32 * SK];   // stripe dbuf / ETT staging
    __shared__ float s_wmax[2][4];

    // ---- stage ETT rows + hoist A-frags (2 rounds of 64 rows through the dbuf) ----
    short8 afr[2][4];                                    // my 32 m-rows x 128 k
#pragma unroll
    for (int round = 0; round < 2; ++round) {
        for (int i = 0; i < 32; ++i) {
            int item = i * 256 + tid;                    // 8192 = 64 rows x 128 k
            int m = item & 63, k = item >> 6;
            s_S[m >> 5][(m & 31) * SK + k] = f2bf(__expf(trans[k * Kk + round * 64 + m]));
        }
        __syncthreads();
        if ((w >> 1) == round) {
            const ushort_t* sb = s_S[w & 1];
#pragma unroll
            for (int mt = 0; mt < 2; ++mt)
#pragma unroll
                for (int kt = 0; kt < 4; ++kt)
                    afr[mt][kt] = *(const short8*)&sb[(mt * 16 + c15) * SK + kt * 32 + q * 8];
        }
        __syncthreads();
    }

    // ---- S0 = identity (stripe cols): s_S[0][nl][k] = (k == nbase+nl) ----
#pragma unroll
    for (int j = 0; j < 2; ++j) {
        int idx = j * 256 + tid;                         // 512 octets: nl = idx>>4, oct = idx&15
        int nl = idx >> 4, oct = idx & 15;
        short8 z = {0, 0, 0, 0, 0, 0, 0, 0};
        int d = nbase + nl - oct * 8;
        if (d >= 0 && d < 8) z[d] = (short)0x3F80;
        *(short8*)&s_S[0][nl * SK + oct * 8] = z;
    }
    if (tid < 4) s_wmax[0][tid] = 1.0f;

    // prefetch first h row (broadcast loads: lanes with same q share addresses)
    const float* hb = &h[((size_t)b * Tt) * Kk];
    float4 hp0 = *(const float4*)&hb[(size_t)ts * Kk + w * 32 + q * 4];
    float4 hp1 = *(const float4*)&hb[(size_t)ts * Kk + w * 32 + 16 + q * 4];
    __syncthreads();

    float Lw = 0.0f;
    int cur = 0;
    for (int t = ts; t < tE; ++t) {
        float4 h0 = hp0, h1 = hp1;
        if (t + 1 < tE) {
            hp0 = *(const float4*)&hb[(size_t)(t + 1) * Kk + w * 32 + q * 4];
            hp1 = *(const float4*)&hb[(size_t)(t + 1) * Kk + w * 32 + 16 + q * 4];
        }
        float G = fmaxf(fmaxf(s_wmax[cur][0], s_wmax[cur][1]),
                        fmaxf(s_wmax[cur][2], s_wmax[cur][3]));
        float invG = 1.0f / G;
        Lw += __logf(G);

        float sc0[4], sc1[4];                            // eh[m]*invG for my 8 rows/lane
        sc0[0] = __expf(h0.x) * invG; sc0[1] = __expf(h0.y) * invG;
        sc0[2] = __expf(h0.z) * invG; sc0[3] = __expf(h0.w) * invG;
        sc1[0] = __expf(h1.x) * invG; sc1[1] = __expf(h1.y) * invG;
        sc1[2] = __expf(h1.z) * invG; sc1[3] = __expf(h1.w) * invG;

        short8 bfr[2][4];                                // stripe B-frags
        const ushort_t* ps = s_S[cur];
#pragma unroll
        for (int nt = 0; nt < 2; ++nt)
#pragma unroll
            for (int kt = 0; kt < 4; ++kt)
                bfr[nt][kt] = *(const short8*)&ps[(nt * 16 + c15) * SK + kt * 32 + q * 8];

        float4v acc[2][2];
#pragma unroll
        for (int mt = 0; mt < 2; ++mt)
#pragma unroll
            for (int nt = 0; nt < 2; ++nt) acc[mt][nt] = (float4v){0.f, 0.f, 0.f, 0.f};
#pragma unroll
        for (int kt = 0; kt < 4; ++kt)
#pragma unroll
            for (int mt = 0; mt < 2; ++mt)
#pragma unroll
                for (int nt = 0; nt < 2; ++nt)
                    acc[mt][nt] = __builtin_amdgcn_mfma_f32_16x16x32_bf16(
                        afr[mt][kt], bfr[nt][kt], acc[mt][nt], 0, 0, 0);

        // epilogue: S_new[m][nl] stored at s_S[nxt][nl][m]; my m = w*32+mt*16+q*4+r
        int nxt = cur ^ 1;
        ushort_t* pn = s_S[nxt];
        float lmax = 0.0f;
#pragma unroll
        for (int mt = 0; mt < 2; ++mt)
#pragma unroll
            for (int nt = 0; nt < 2; ++nt) {
                float v0 = acc[mt][nt][0] * (mt ? sc1[0] : sc0[0]);
                float v1 = acc[mt][nt][1] * (mt ? sc1[1] : sc0[1]);
                float v2 = acc[mt][nt][2] * (mt ? sc1[2] : sc0[2]);
                float v3 = acc[mt][nt][3] * (mt ? sc1[3] : sc0[3]);
                lmax = fmaxf(lmax, fmaxf(fmaxf(v0, v1), fmaxf(v2, v3)));
                uint2 u; u.x = pk2bf(v0, v1); u.y = pk2bf(v2, v3);
                *(uint2*)&pn[(nt * 16 + c15) * SK + w * 32 + mt * 16 + q * 4] = u;
            }
#pragma unroll
        for (int o = 1; o < 64; o <<= 1) lmax = fmaxf(lmax, __shfl_xor(lmax, o));
        if (lane == 0) s_wmax[nxt][w] = lmax;
        __syncthreads();
        cur = nxt;
    }

    // ---- dump (verified R6/R7 orientation): Qt[n][nbase+kl] = S[n][nbase+kl] = s_S[kl][n] ----
    float Gf = fmaxf(fmaxf(s_wmax[cur][0], s_wmax[cur][1]),
                     fmaxf(s_wmax[cur][2], s_wmax[cur][3]));
    float dsc = 1.0f / Gf;
    Lw += __logf(Gf);
    const ushort_t* pc = s_S[cur];
#pragma unroll
    for (int j = 0; j < 2; ++j) {
        int idx = j * 256 + tid;                         // n = idx&127 (lane-consecutive), o = idx>>7
        int n = idx & 127, o = idx >> 7;
        uint4 gv; ushort_t* gp = (ushort_t*)&gv;
#pragma unroll
        for (int r = 0; r < 8; ++r)
            gp[r] = f2bf(bf2f(pc[(o * 8 + r) * SK + n]) * dsc);
        *(uint4*)&Qt[qoff + (size_t)n * Kk + nbase + o * 8] = gv;
    }
    if (tid == 0) Ls[(((size_t)b * NC + c) << 2) + st] = Lw;
}

// ---------------- stage B: vector chain with per-stripe scales ----------------
// v_new[n] = sum_st e^{Ls_st - Lref} * sum_{k in st} v[k] * Qt[n][k]; gold fused;
// register prefetch of chunk ci+1 during chunk ci (R8-proven).
__global__ __launch_bounds__(256, 1) void crf_stageB(const float* __restrict__ h,
                                                     const float* __restrict__ trans,
                                                     const int* __restrict__ y,
                                                     const int* __restrict__ lengths,
                                                     const ushort_t* __restrict__ Qt,
                                                     const float* __restrict__ Ls,
                                                     float* __restrict__ out, int NC) {
    const int b = blockIdx.x;
    const int tid = threadIdx.x;
    const int lane = tid & 63, w = tid >> 6;
    const int n = tid >> 1, half = tid & 1;
    const int len = lengths[b];

    __shared__ __align__(16) float vbuf[2][Kk];
    __shared__ float s_wmax[2][4];
    __shared__ float red[4];
    __shared__ float gred[4];

    // ---- fused gold score ----
    {
        float g = 0.0f;
        if (tid < len) {
            int yt   = y[b * Tt + tid];
            int prev = (tid == 0) ? SOS_IDX : y[b * Tt + tid - 1];
            g = h[((size_t)b * Tt + tid) * Kk + yt] + trans[prev * Kk + yt];
        }
#pragma unroll
        for (int off = 32; off > 0; off >>= 1) g += __shfl_down(g, off);
        if (lane == 0) gred[w] = g;
    }

    // ---- init v0 = exp(alpha0 - m0) ----
    float a0 = h[((size_t)b * Tt) * Kk + n] + trans[SOS_IDX * Kk + n];
    float m0 = a0;
#pragma unroll
    for (int o = 1; o < 64; o <<= 1) m0 = fmaxf(m0, __shfl_xor(m0, o));
    if (lane == 0) red[w] = m0;
    __syncthreads();
    m0 = fmaxf(fmaxf(red[0], red[1]), fmaxf(red[2], red[3]));
    float cacc = m0;
    if (half == 0) vbuf[0][n] = __expf(a0 - m0);
    if (tid < 4) s_wmax[0][tid] = 1.0f;
    if (tid == 0)
        atomicAdd(out, -(gred[0] + gred[1] + gred[2] + gred[3]) * (1.0f / (float)Bb));
    __syncthreads();

    const size_t lbase = (size_t)b * NC;
    uint4 qb[8];
    {
        const uint4* qp = (const uint4*)(Qt + lbase * (Kk * Kk) + n * Kk + half * 64);
#pragma unroll
        for (int r = 0; r < 8; ++r) qb[r] = qp[r];
    }

    int cur = 0;
    for (int ci = 0; ci < NC; ++ci) {
        uint4 qn[8];
        if (ci + 1 < NC) {
            const uint4* qp2 = (const uint4*)(Qt + (lbase + ci + 1) * (Kk * Kk) + n * Kk + half * 64);
#pragma unroll
            for (int r = 0; r < 8; ++r) qn[r] = qp2[r];
        }
        float4 Ls4 = *(const float4*)&Ls[(lbase + ci) << 2];     // 4 stripe log-scales
        float Lref = fmaxf(fmaxf(Ls4.x, Ls4.y), fmaxf(Ls4.z, Ls4.w));
        float eA = __expf((half ? Ls4.z : Ls4.x) - Lref);        // stripe 2*half
        float eB = __expf((half ? Ls4.w : Ls4.y) - Lref);        // stripe 2*half+1

        float G = fmaxf(fmaxf(s_wmax[cur][0], s_wmax[cur][1]),
                        fmaxf(s_wmax[cur][2], s_wmax[cur][3]));
        float invG = 1.0f / G;
        cacc += __logf(G) + Lref;

        float aA0 = 0.f, aA1 = 0.f, aB0 = 0.f, aB1 = 0.f;       // per-stripe partials
#pragma unroll
        for (int r = 0; r < 8; ++r) {
            uint4 d = qb[r];
            float4 v0 = *(const float4*)&vbuf[cur][half * 64 + r * 8];
            float4 v1 = *(const float4*)&vbuf[cur][half * 64 + r * 8 + 4];
            float* p0 = (r < 4) ? &aA0 : &aB0;
            float* p1 = (r < 4) ? &aA1 : &aB1;
            *p0 = fmaf(bflo(d.x), v0.x, *p0);
            *p1 = fmaf(bfhi(d.x), v0.y, *p1);
            *p0 = fmaf(bflo(d.y), v0.z, *p0);
            *p1 = fmaf(bfhi(d.y), v0.w, *p1);
            *p0 = fmaf(bflo(d.z), v1.x, *p0);
            *p1 = fmaf(bfhi(d.z), v1.y, *p1);
            *p0 = fmaf(bflo(d.w), v1.z, *p0);
            *p1 = fmaf(bfhi(d.w), v1.w, *p1);
        }
        float s = (fmaf(eA, aA0 + aA1, eB * (aB0 + aB1))) * invG;
        s += __shfl_xor(s, 1);                                   // pair combine

        float wm = s;
#pragma unroll
        for (int o = 1; o < 64; o <<= 1) wm = fmaxf(wm, __shfl_xor(wm, o));
        int nxt = cur ^ 1;
        if (half == 0) vbuf[nxt][n] = s;
        if (lane == 0) s_wmax[nxt][w] = wm;
        __syncthreads();
        cur = nxt;
        if (ci + 1 < NC) {
#pragma unroll
            for (int r = 0; r < 8; ++r) qb[r] = qn[r];
        }
    }

    if (tid == 0) {
        atomicAdd(out, (cacc + __logf(vbuf[cur][EOS_IDX])) * (1.0f / (float)Bb));
    }
}

extern "C" void kernel_launch(void* const* d_in, const int* in_sizes, int n_in,
                              void* d_out, int out_size, void* d_ws, size_t ws_size,
                              hipStream_t stream) {
    const float* h       = (const float*)d_in[0];
    const float* trans   = (const float*)d_in[1];
    const int*   y       = (const int*)d_in[2];
    const int*   lengths = (const int*)d_in[3];
    // d_in[4] = mask: derived from lengths instead.
    float* out = (float*)d_out;

    int NC = 8;                                    // 8 chunks x 4 stripes -> 1024 blocks (4/CU)
    while (NC > 1) {
        size_t need = (size_t)Bb * NC * Kk * Kk * 2 + (size_t)Bb * NC * 16;
        if (need <= ws_size) break;
        NC >>= 1;
    }
    int CSPAN = Tt / NC;
    ushort_t* Qt = (ushort_t*)d_ws;
    float* Ls = (float*)((char*)d_ws + (size_t)Bb * NC * Kk * Kk * 2);

    hipMemsetAsync(out, 0, sizeof(float), stream);
    crf_stageA<<<dim3(4, NC, Bb), 256, 0, stream>>>(h, trans, lengths, Qt, Ls, NC, CSPAN);
    crf_stageB<<<Bb, 256, 0, stream>>>(h, trans, y, lengths, Qt, Ls, out, NC);
}

// Round 10
// 114.953 us; speedup vs baseline: 1.4815x; 1.1895x over previous
//
#include <hip/hip_runtime.h>
#include <stdint.h>

#define SOS_IDX 1
#define EOS_IDX 2
#define Bb 32
#define Tt 256
#define Kk 128
#define SK 136          // padded k-stride in ushorts (272 B) -> conflict-free b64/b128

typedef unsigned short ushort_t;
typedef __attribute__((ext_vector_type(8))) short short8;   // 8 bf16 = 4 VGPR (MFMA A/B)
typedef __attribute__((ext_vector_type(4))) float float4v;  // MFMA C/D

__device__ __forceinline__ ushort_t f2bf(float x) {         // RNE
    union { float f; uint32_t u; } c; c.f = x;
    uint32_t u = c.u + 0x7FFFu + ((c.u >> 16) & 1u);
    return (ushort_t)(u >> 16);
}
__device__ __forceinline__ float bf2f(ushort_t s) {
    union { uint32_t u; float f; } c; c.u = ((uint32_t)s) << 16;
    return c.f;
}
__device__ __forceinline__ float bflo(uint32_t u) {
    union { uint32_t u; float f; } c; c.u = u << 16; return c.f;
}
__device__ __forceinline__ float bfhi(uint32_t u) {
    union { uint32_t u; float f; } c; c.u = u & 0xFFFF0000u; return c.f;
}
__device__ __forceinline__ uint32_t pk2bf(float a, float b) {   // 2x f32 -> bf16x2, RNE
    union { float f; uint32_t u; } ca, cb; ca.f = a; cb.f = b;
    uint32_t ua = ca.u + 0x7FFFu + ((ca.u >> 16) & 1u);
    uint32_t ub = cb.u + 0x7FFFu + ((cb.u >> 16) & 1u);
    return __builtin_amdgcn_perm(ub, ua, 0x07060302u);
}

// ---------------- stage A: block = (stripe, chunk, batch); R9-verified layouts ------
// Changes vs R9 (which measured 60.5 us, Occupancy 11.8%, absmax 0.0):
//  * NC=16 -> 16-step chains, 2048 blocks, ~6 resident/CU (LDS 25.6 KB)
//  * rescale every 4th step only (bf16 max 3.4e38, growth <~3e4/step -> 7 unscaled
//    steps peak ~1e32, safe). Kills shfl-max/log/rcp/invG on 3 of 4 steps.
//    s_wmax dbuf'd by mark parity ((s>>2)&1) -- apply step s=4k reads slot (k-1)&1
//    while a same-step final-mark writes slot k&1 (no race).
//  * eh = exp(h) raw (NO max subtraction), prestaged to LDS bf16 once per chunk.
//  * masked chunks: exit with NO writes (stage B skips them via lengths).
__global__ __launch_bounds__(256, 2) void crf_stageA(const float* __restrict__ h,
                                                     const float* __restrict__ trans,
                                                     const int* __restrict__ lengths,
                                                     ushort_t* __restrict__ Qt,
                                                     float* __restrict__ Ls,
                                                     int NC, int CSPAN) {
    const int st = blockIdx.x, c = blockIdx.y, b = blockIdx.z;
    const int tid = threadIdx.x;
    const int lane = tid & 63, w = tid >> 6;
    const int c15 = lane & 15, q = lane >> 4;
    const int len = lengths[b];
    int ts = c * CSPAN; if (ts < 1) ts = 1;
    int te = (c + 1) * CSPAN; if (te > Tt) te = Tt;
    const int tE = te < len ? te : len;
    if (ts >= tE) return;                       // masked chunk: no work, no writes
    const int nsteps = tE - ts;
    const size_t qoff = ((size_t)b * NC + c) * (Kk * Kk);
    const int nbase = st * 32;

    __shared__ __align__(16) ushort_t s_S[2][32 * SK];   // stripe dbuf / ETT staging
    __shared__ __align__(16) ushort_t s_ehb[32][Kk];     // exp(h) per step, bf16
    __shared__ float s_wmax[2][4];                       // dbuf by mark parity

    // ---- eh staging (raw exp, no hm) ----
    for (int tl = w; tl < nsteps; tl += 4) {
        const float* hr = &h[((size_t)b * Tt + ts + tl) * Kk];
        s_ehb[tl][lane]      = f2bf(__expf(hr[lane]));
        s_ehb[tl][lane + 64] = f2bf(__expf(hr[lane + 64]));
    }

    // ---- ETT staging + A-frag hoist (R9-verified 2-round dance) ----
    short8 afr[2][4];
#pragma unroll
    for (int round = 0; round < 2; ++round) {
        for (int i = 0; i < 32; ++i) {
            int item = i * 256 + tid;
            int m = item & 63, k = item >> 6;
            s_S[m >> 5][(m & 31) * SK + k] = f2bf(__expf(trans[k * Kk + round * 64 + m]));
        }
        __syncthreads();
        if ((w >> 1) == round) {
            const ushort_t* sb = s_S[w & 1];
#pragma unroll
            for (int mt = 0; mt < 2; ++mt)
#pragma unroll
                for (int kt = 0; kt < 4; ++kt)
                    afr[mt][kt] = *(const short8*)&sb[(mt * 16 + c15) * SK + kt * 32 + q * 8];
        }
        __syncthreads();
    }

    // ---- S0 = identity (stripe cols), R9-verified ----
#pragma unroll
    for (int j = 0; j < 2; ++j) {
        int idx = j * 256 + tid;
        int nl = idx >> 4, oct = idx & 15;
        short8 z = {0, 0, 0, 0, 0, 0, 0, 0};
        int d = nbase + nl - oct * 8;
        if (d >= 0 && d < 8) z[d] = (short)0x3F80;
        *(short8*)&s_S[0][nl * SK + oct * 8] = z;
    }
    __syncthreads();

    float L = 0.0f;
    int cur = 0;
    for (int s = 0; s < nsteps; ++s) {
        float invG = 1.0f;
        if (s > 0 && (s & 3) == 0) {                     // apply (reads mark at s-1)
            int ms = ((s >> 2) - 1) & 1;
            float g = fmaxf(fmaxf(s_wmax[ms][0], s_wmax[ms][1]),
                            fmaxf(s_wmax[ms][2], s_wmax[ms][3]));
            invG = 1.0f / g;
            L += __logf(g);
        }
        const bool isMark = ((s & 3) == 3) || (s == nsteps - 1);

        // eh for my 8 rows (broadcast b64 LDS reads)
        float sc0[4], sc1[4];
        {
            uint2 u0 = *(const uint2*)&s_ehb[s][w * 32 + q * 4];
            uint2 u1 = *(const uint2*)&s_ehb[s][w * 32 + 16 + q * 4];
            sc0[0] = bflo(u0.x) * invG; sc0[1] = bfhi(u0.x) * invG;
            sc0[2] = bflo(u0.y) * invG; sc0[3] = bfhi(u0.y) * invG;
            sc1[0] = bflo(u1.x) * invG; sc1[1] = bfhi(u1.x) * invG;
            sc1[2] = bflo(u1.y) * invG; sc1[3] = bfhi(u1.y) * invG;
        }

        short8 bfr[2][4];                                // stripe B-frags (R9-verified)
        const ushort_t* ps = s_S[cur];
#pragma unroll
        for (int nt = 0; nt < 2; ++nt)
#pragma unroll
            for (int kt = 0; kt < 4; ++kt)
                bfr[nt][kt] = *(const short8*)&ps[(nt * 16 + c15) * SK + kt * 32 + q * 8];

        float4v acc[2][2];
#pragma unroll
        for (int mt = 0; mt < 2; ++mt)
#pragma unroll
            for (int nt = 0; nt < 2; ++nt) acc[mt][nt] = (float4v){0.f, 0.f, 0.f, 0.f};
#pragma unroll
        for (int kt = 0; kt < 4; ++kt)
#pragma unroll
            for (int mt = 0; mt < 2; ++mt)
#pragma unroll
                for (int nt = 0; nt < 2; ++nt)
                    acc[mt][nt] = __builtin_amdgcn_mfma_f32_16x16x32_bf16(
                        afr[mt][kt], bfr[nt][kt], acc[mt][nt], 0, 0, 0);

        // epilogue (R9-verified addressing)
        int nxt = cur ^ 1;
        ushort_t* pn = s_S[nxt];
        float lmax = 0.0f;
#pragma unroll
        for (int mt = 0; mt < 2; ++mt)
#pragma unroll
            for (int nt = 0; nt < 2; ++nt) {
                float v0 = acc[mt][nt][0] * (mt ? sc1[0] : sc0[0]);
                float v1 = acc[mt][nt][1] * (mt ? sc1[1] : sc0[1]);
                float v2 = acc[mt][nt][2] * (mt ? sc1[2] : sc0[2]);
                float v3 = acc[mt][nt][3] * (mt ? sc1[3] : sc0[3]);
                lmax = fmaxf(lmax, fmaxf(fmaxf(v0, v1), fmaxf(v2, v3)));
                uint2 u; u.x = pk2bf(v0, v1); u.y = pk2bf(v2, v3);
                *(uint2*)&pn[(nt * 16 + c15) * SK + w * 32 + mt * 16 + q * 4] = u;
            }
        if (isMark) {
#pragma unroll
            for (int o = 1; o < 64; o <<= 1) lmax = fmaxf(lmax, __shfl_xor(lmax, o));
            if (lane == 0) s_wmax[(s >> 2) & 1][w] = lmax;
        }
        __syncthreads();
        cur = nxt;
    }

    // ---- dump (R9-verified orientation): Qt[n][nbase+kl] = s_S[kl][n] ----
    int fs = ((nsteps - 1) >> 2) & 1;
    float Gf = fmaxf(fmaxf(s_wmax[fs][0], s_wmax[fs][1]),
                     fmaxf(s_wmax[fs][2], s_wmax[fs][3]));
    float dsc = 1.0f / Gf;
    L += __logf(Gf);
    const ushort_t* pc = s_S[cur];
#pragma unroll
    for (int j = 0; j < 2; ++j) {
        int idx = j * 256 + tid;
        int n = idx & 127, o = idx >> 7;
        uint4 gv; ushort_t* gp = (ushort_t*)&gv;
#pragma unroll
        for (int r = 0; r < 8; ++r)
            gp[r] = f2bf(bf2f(pc[(o * 8 + r) * SK + n]) * dsc);
        *(uint4*)&Qt[qoff + (size_t)n * Kk + nbase + o * 8] = gv;
    }
    if (tid == 0) Ls[(((size_t)b * NC + c) << 2) + st] = L;
}

// ---------------- stage B: 512-thread vector chain, masked chunks skipped ----------
// 4 lanes per state n (quarter = tid&3 dots k in [32q,32q+32) = stripe q, so the
// per-stripe scale is a single per-lane factor). Register prefetch of chunk ci+1;
// every-4 rescale (growth <= 128x/chunk -> 4 chunks = 2.7e8, f32-safe).
__global__ __launch_bounds__(512, 1) void crf_stageB(const float* __restrict__ h,
                                                     const float* __restrict__ trans,
                                                     const int* __restrict__ y,
                                                     const int* __restrict__ lengths,
                                                     const ushort_t* __restrict__ Qt,
                                                     const float* __restrict__ Ls,
                                                     float* __restrict__ out,
                                                     int NC, int CSPAN) {
    const int b = blockIdx.x;
    const int tid = threadIdx.x;
    const int lane = tid & 63, w = tid >> 6;
    const int n = tid >> 2, qr = tid & 3;
    const int len = lengths[b];

    __shared__ __align__(16) float vbuf[2][Kk];
    __shared__ float s_wmax[2][8];
    __shared__ float red[8];
    __shared__ float gred[4];

    // ---- fused gold score (waves 0..3 cover t = tid in [0,256)) ----
    if (w < 4) {
        float g = 0.0f;
        if (tid < len) {
            int yt   = y[b * Tt + tid];
            int prev = (tid == 0) ? SOS_IDX : y[b * Tt + tid - 1];
            g = h[((size_t)b * Tt + tid) * Kk + yt] + trans[prev * Kk + yt];
        }
#pragma unroll
        for (int off = 32; off > 0; off >>= 1) g += __shfl_down(g, off);
        if (lane == 0) gred[w] = g;
    }

    // ---- init v0 = exp(alpha0 - m0) ----
    float a0 = h[((size_t)b * Tt) * Kk + n] + trans[SOS_IDX * Kk + n];
    float m0 = a0;
#pragma unroll
    for (int o = 1; o < 64; o <<= 1) m0 = fmaxf(m0, __shfl_xor(m0, o));
    if (lane == 0) red[w] = m0;
    __syncthreads();
    {
        float4 r0 = *(const float4*)&red[0];
        float4 r1 = *(const float4*)&red[4];
        m0 = fmaxf(fmaxf(fmaxf(r0.x, r0.y), fmaxf(r0.z, r0.w)),
                   fmaxf(fmaxf(r1.x, r1.y), fmaxf(r1.z, r1.w)));
    }
    float cacc = m0;
    if (qr == 0) vbuf[0][n] = __expf(a0 - m0);

    const int NCR = (len <= 1) ? 0 : min(NC, (len + CSPAN - 1) / CSPAN);
    const size_t lbase = (size_t)b * NC;
    uint4 qb[4];
    if (NCR > 0) {
        const uint4* qp = (const uint4*)(Qt + lbase * (Kk * Kk) + n * Kk + qr * 32);
#pragma unroll
        for (int r = 0; r < 4; ++r) qb[r] = qp[r];
    }
    __syncthreads();
    if (tid == 0)
        atomicAdd(out, -(gred[0] + gred[1] + gred[2] + gred[3]) * (1.0f / (float)Bb));

    int cur = 0;
    for (int ci = 0; ci < NCR; ++ci) {
        uint4 qn[4];
        if (ci + 1 < NCR) {
            const uint4* qp2 = (const uint4*)(Qt + (lbase + ci + 1) * (Kk * Kk) + n * Kk + qr * 32);
#pragma unroll
            for (int r = 0; r < 4; ++r) qn[r] = qp2[r];
        }
        float4 Ls4 = *(const float4*)&Ls[(lbase + ci) << 2];
        float Lref = fmaxf(fmaxf(Ls4.x, Ls4.y), fmaxf(Ls4.z, Ls4.w));
        float lsq = (qr == 0) ? Ls4.x : (qr == 1) ? Ls4.y : (qr == 2) ? Ls4.z : Ls4.w;
        float eQ = __expf(lsq - Lref);
        float invG = 1.0f;
        if (ci > 0 && (ci & 3) == 0) {                   // apply
            int ms = ((ci >> 2) - 1) & 1;
            float4 r0 = *(const float4*)&s_wmax[ms][0];
            float4 r1 = *(const float4*)&s_wmax[ms][4];
            float g = fmaxf(fmaxf(fmaxf(r0.x, r0.y), fmaxf(r0.z, r0.w)),
                            fmaxf(fmaxf(r1.x, r1.y), fmaxf(r1.z, r1.w)));
            invG = 1.0f / g;
            cacc += __logf(g);
        }
        cacc += Lref;

        float acc0 = 0.0f, acc1 = 0.0f;
#pragma unroll
        for (int r = 0; r < 4; ++r) {
            uint4 d = qb[r];
            float4 v0 = *(const float4*)&vbuf[cur][qr * 32 + r * 8];
            float4 v1 = *(const float4*)&vbuf[cur][qr * 32 + r * 8 + 4];
            acc0 = fmaf(bflo(d.x), v0.x, acc0);
            acc1 = fmaf(bfhi(d.x), v0.y, acc1);
            acc0 = fmaf(bflo(d.y), v0.z, acc0);
            acc1 = fmaf(bfhi(d.y), v0.w, acc1);
            acc0 = fmaf(bflo(d.z), v1.x, acc0);
            acc1 = fmaf(bfhi(d.z), v1.y, acc1);
            acc0 = fmaf(bflo(d.w), v1.z, acc0);
            acc1 = fmaf(bfhi(d.w), v1.w, acc1);
        }
        float s = (acc0 + acc1) * (eQ * invG);
        s += __shfl_xor(s, 1);                           // combine 4 quarters
        s += __shfl_xor(s, 2);

        const bool isMark = ((ci & 3) == 3) || (ci == NCR - 1);
        if (isMark) {
            float wm = s;
#pragma unroll
            for (int o = 1; o < 64; o <<= 1) wm = fmaxf(wm, __shfl_xor(wm, o));
            if (lane == 0) s_wmax[(ci >> 2) & 1][w] = wm;
        }
        int nxt = cur ^ 1;
        if (qr == 0) vbuf[nxt][n] = s;
        __syncthreads();
        cur = nxt;
        if (ci + 1 < NCR) {
#pragma unroll
            for (int r = 0; r < 4; ++r) qb[r] = qn[r];
        }
    }

    // Z_b = cacc + log(v_final[EOS])  (pending un-applied G is still inside v)
    if (tid == 0) {
        atomicAdd(out, (cacc + __logf(vbuf[cur][EOS_IDX])) * (1.0f / (float)Bb));
    }
}

extern "C" void kernel_launch(void* const* d_in, const int* in_sizes, int n_in,
                              void* d_out, int out_size, void* d_ws, size_t ws_size,
                              hipStream_t stream) {
    const float* h       = (const float*)d_in[0];
    const float* trans   = (const float*)d_in[1];
    const int*   y       = (const int*)d_in[2];
    const int*   lengths = (const int*)d_in[3];
    // d_in[4] = mask: derived from lengths instead.
    float* out = (float*)d_out;

    int NC = 16;                                  // 16 chunks x 16 steps; floor 8 (s_ehb cap 32)
    while (NC > 8) {
        size_t need = (size_t)Bb * NC * Kk * Kk * 2 + (size_t)Bb * NC * 16;
        if (need <= ws_size) break;
        NC >>= 1;
    }
    int CSPAN = Tt / NC;
    ushort_t* Qt = (ushort_t*)d_ws;
    float* Ls = (float*)((char*)d_ws + (size_t)Bb * NC * Kk * Kk * 2);

    hipMemsetAsync(out, 0, sizeof(float), stream);
    crf_stageA<<<dim3(4, NC, Bb), 256, 0, stream>>>(h, trans, lengths, Qt, Ls, NC, CSPAN);
    crf_stageB<<<Bb, 512, 0, stream>>>(h, trans, y, lengths, Qt, Ls, out, NC, CSPAN);
}